// Round 1
// baseline (458.781 us; speedup 1.0000x reference)
//
#include <hip/hip_runtime.h>

typedef unsigned short u16;
typedef __attribute__((ext_vector_type(8))) short bf16x8;
typedef __attribute__((ext_vector_type(4))) float f32x4;
typedef __attribute__((ext_vector_type(16))) float f32x16;
typedef __attribute__((ext_vector_type(4))) unsigned u32x4;

#define DEV static __device__ __forceinline__

DEV u16 f2bf(float f) {
    unsigned u = __float_as_uint(f);
    u += 0x7FFFu + ((u >> 16) & 1u);
    return (u16)(u >> 16);
}

typedef const __attribute__((address_space(1))) void* gas1_t;
typedef __attribute__((address_space(3))) void* gas3_t;

DEV void gl_lds16(const u16* g, u16* l) {
    __builtin_amdgcn_global_load_lds((gas1_t)g, (gas3_t)l, 16, 0, 0);
}

DEV unsigned cvtpk_bf16(float a, float b) {
    unsigned r;
    asm("v_cvt_pk_bf16_f32 %0, %1, %2" : "=v"(r) : "v"(a), "v"(b));
    return r;
}

// swizzled LDS offset (u16 units) for 128B rows of 64 u16, 16B chunks
DEV int sw8(int row, int chunk) { return row * 64 + ((chunk ^ (row & 7)) << 3); }

// ---------------- merged prep: weight casts + bias permute + mask pack ----------------
// block ranges: [0,3072) qkvW | [3072,4096) oW | [4096,8192) p1W | [8192,12288) p2W
//               | [12288,20480) mask pack | 20480 pbias
__global__ __launch_bounds__(256) void prep_all(const float* __restrict__ qkv_w,
                                                const float* __restrict__ o_w,
                                                const float* __restrict__ p1_w,
                                                const float* __restrict__ p2_w,
                                                const float* __restrict__ qkv_b,
                                                const float* __restrict__ nm,
                                                const float* __restrict__ pm,
                                                u16* __restrict__ qkvW,
                                                u16* __restrict__ oW,
                                                u16* __restrict__ p1W,
                                                u16* __restrict__ p2W,
                                                float* __restrict__ pbias,
                                                unsigned* __restrict__ Mp) {
    const int bid = blockIdx.x, t = threadIdx.x;
    if (bid < 3072) {            // qkv cast + row permute: rows = [V|Q|K], each h*64+t
        int i = bid * 256 + t;
        int orow = i >> 8, cc = i & 255;
        int region = orow >> 10, rem = orow & 1023, h = rem >> 6, tt = rem & 63;
        int srow = h * 192 + region * 64 + tt;
        float4 v = ((const float4*)qkv_w)[srow * 256 + cc];
        ushort4 o;
        o.x = f2bf(v.x); o.y = f2bf(v.y); o.z = f2bf(v.z); o.w = f2bf(v.w);
        ((ushort4*)qkvW)[i] = o;
    } else if (bid < 4096) {     // o_w cast
        int i = (bid - 3072) * 256 + t;
        float4 v = ((const float4*)o_w)[i];
        ushort4 o;
        o.x = f2bf(v.x); o.y = f2bf(v.y); o.z = f2bf(v.z); o.w = f2bf(v.w);
        ((ushort4*)oW)[i] = o;
    } else if (bid < 8192) {     // p1_w cast
        int i = (bid - 4096) * 256 + t;
        float4 v = ((const float4*)p1_w)[i];
        ushort4 o;
        o.x = f2bf(v.x); o.y = f2bf(v.y); o.z = f2bf(v.z); o.w = f2bf(v.w);
        ((ushort4*)p1W)[i] = o;
    } else if (bid < 12288) {    // p2_w cast
        int i = (bid - 8192) * 256 + t;
        float4 v = ((const float4*)p2_w)[i];
        ushort4 o;
        o.x = f2bf(v.x); o.y = f2bf(v.y); o.z = f2bf(v.z); o.w = f2bf(v.w);
        ((ushort4*)p2W)[i] = o;
    } else if (bid < 20480) {    // mask pack, permuted for 32x32 MFMA C-layout
        int i = (bid - 12288) * 256 + t;           // uint4 index; 4 consecutive m
        float4 a = ((const float4*)nm)[i];
        float4 b = ((const float4*)pm)[i];
        uint4 o;
        o.x = ((unsigned)f2bf(b.x) << 16) | f2bf(a.x * 1.4426950f);
        o.y = ((unsigned)f2bf(b.y) << 16) | f2bf(a.y * 1.4426950f);
        o.z = ((unsigned)f2bf(b.z) << 16) | f2bf(a.z * 1.4426950f);
        o.w = ((unsigned)f2bf(b.w) << 16) | f2bf(a.w * 1.4426950f);
        // decode (b,n,m) and write to [b][mt=m/32][n][hi][reg] with
        // m = (reg&3) + 8*(reg>>2) + 4*hi  (32x32x16 C-row mapping)
        int e = i * 4;
        int bb = e >> 22;
        int rem = e & 4194303;
        int n = rem >> 11;
        int m = rem & 2047;
        int mt = m >> 5;
        int j = m & 31;                 // multiple of 4
        int hi = (j >> 2) & 1;
        int rb4 = j >> 3;               // uint4 slot within the 16-reg group
        size_t oi = (((size_t)(bb * 64 + mt) * 2048 + n) * 2 + hi) * 4 + rb4;
        ((uint4*)Mp)[oi] = o;
    } else {                     // qkv bias permute (3072 elements)
#pragma unroll
        for (int k = 0; k < 12; k++) {
            int i = k * 256 + t;
            int region = i >> 10, rem = i & 1023, h = rem >> 6, tt = rem & 63;
            pbias[i] = qkv_b[h * 192 + region * 64 + tt];
        }
    }
}

// ---------------- LayerNorm (D=1024) f32 -> bf16 ----------------
__global__ __launch_bounds__(256) void ln_bf16(const float* __restrict__ x,
                                               const float* __restrict__ gam,
                                               const float* __restrict__ bet,
                                               u16* __restrict__ y) {
    const int row = blockIdx.x;
    const int t = threadIdx.x;
    const float4 v = ((const float4*)(x + (size_t)row * 1024))[t];
    float s = v.x + v.y + v.z + v.w;
    float ss = v.x * v.x + v.y * v.y + v.z * v.z + v.w * v.w;
#pragma unroll
    for (int o = 1; o < 64; o <<= 1) {
        s += __shfl_xor(s, o);
        ss += __shfl_xor(ss, o);
    }
    __shared__ float rs[4], rss[4];
    const int wave = t >> 6, lane = t & 63;
    if (lane == 0) { rs[wave] = s; rss[wave] = ss; }
    __syncthreads();
    const float tot = rs[0] + rs[1] + rs[2] + rs[3];
    const float totss = rss[0] + rss[1] + rss[2] + rss[3];
    const float mu = tot * (1.0f / 1024.0f);
    const float var = totss * (1.0f / 1024.0f) - mu * mu;
    const float rstd = rsqrtf(var + 1e-5f);
    const float4 g4 = ((const float4*)gam)[t];
    const float4 b4 = ((const float4*)bet)[t];
    ushort4 o;
    o.x = f2bf((v.x - mu) * rstd * g4.x + b4.x);
    o.y = f2bf((v.y - mu) * rstd * g4.y + b4.y);
    o.z = f2bf((v.z - mu) * rstd * g4.z + b4.z);
    o.w = f2bf((v.w - mu) * rstd * g4.w + b4.w);
    ((ushort4*)(y + (size_t)row * 1024))[t] = o;
}

// ---- fused 4-way combine + residual + LayerNorm ----
__global__ __launch_bounds__(256) void ln2_comb4(const float* __restrict__ p0,
                                                 const float* __restrict__ p1,
                                                 const float* __restrict__ p2,
                                                 const float* __restrict__ p3,
                                                 const float* __restrict__ Z,
                                                 const float* __restrict__ gam,
                                                 const float* __restrict__ bet,
                                                 float* __restrict__ Z1,
                                                 u16* __restrict__ y) {
    const int row = blockIdx.x;
    const int t = threadIdx.x;
    const size_t off = (size_t)row * 256 + t;
    const float4 a = ((const float4*)p0)[off];
    const float4 c = ((const float4*)p1)[off];
    const float4 d = ((const float4*)p2)[off];
    const float4 e = ((const float4*)p3)[off];
    const float4 z = ((const float4*)Z)[off];
    float4 v;
    v.x = a.x + c.x + d.x + e.x + z.x;
    v.y = a.y + c.y + d.y + e.y + z.y;
    v.z = a.z + c.z + d.z + e.z + z.z;
    v.w = a.w + c.w + d.w + e.w + z.w;
    ((float4*)Z1)[off] = v;
    float s = v.x + v.y + v.z + v.w;
    float ss = v.x * v.x + v.y * v.y + v.z * v.z + v.w * v.w;
#pragma unroll
    for (int o = 1; o < 64; o <<= 1) {
        s += __shfl_xor(s, o);
        ss += __shfl_xor(ss, o);
    }
    __shared__ float rs[4], rss[4];
    const int wave = t >> 6, lane = t & 63;
    if (lane == 0) { rs[wave] = s; rss[wave] = ss; }
    __syncthreads();
    const float tot = rs[0] + rs[1] + rs[2] + rs[3];
    const float totss = rss[0] + rss[1] + rss[2] + rss[3];
    const float mu = tot * (1.0f / 1024.0f);
    const float var = totss * (1.0f / 1024.0f) - mu * mu;
    const float rstd = rsqrtf(var + 1e-5f);
    const float4 g4 = ((const float4*)gam)[t];
    const float4 b4 = ((const float4*)bet)[t];
    ushort4 o;
    o.x = f2bf((v.x - mu) * rstd * g4.x + b4.x);
    o.y = f2bf((v.y - mu) * rstd * g4.y + b4.y);
    o.z = f2bf((v.z - mu) * rstd * g4.z + b4.z);
    o.w = f2bf((v.w - mu) * rstd * g4.w + b4.w);
    ((ushort4*)(y + (size_t)row * 1024))[t] = o;
}

// ---- final combine: out = p0 + p1 + bias + Z1 ----
__global__ __launch_bounds__(256) void out_comb(const float* __restrict__ p0,
                                                const float* __restrict__ p1,
                                                const float* __restrict__ bias,
                                                const float* __restrict__ Z1,
                                                float* __restrict__ out) {
    int i = blockIdx.x * 256 + threadIdx.x;   // 1048576 float4s
    float4 a = ((const float4*)p0)[i];
    float4 c = ((const float4*)p1)[i];
    float4 z = ((const float4*)Z1)[i];
    float4 b = ((const float4*)bias)[i & 255];
    float4 o;
    o.x = a.x + c.x + z.x + b.x; o.y = a.y + c.y + z.y + b.y;
    o.z = a.z + c.z + z.z + b.z; o.w = a.w + c.w + z.w + b.w;
    ((float4*)out)[i] = o;
}

// ---------------- GEMM: C[M,N] = A[M,K-slice] @ Bt[N,K-slice]^T ----------------
// 128x128 tile, BK=32. ldk = row stride; K = slice length; slice start = z*K.
// EPI 0: +pbias; region: 0 -> f32 Vsc(out0), 1 -> Q bf16(out1), 2 -> K bf16(out2)
// EPI 2: +bias, relu, write bf16 out0
// EPI 4: raw f32 partial -> (z<2 ? out0 : out1) + (z&1)*M*N
template <int EPI>
__global__ __launch_bounds__(256, 3) void gemm_bt(const u16* __restrict__ A,
                                                  const u16* __restrict__ Bt,
                                                  const float* __restrict__ bias,
                                                  void* __restrict__ out0,
                                                  void* __restrict__ out1,
                                                  void* __restrict__ out2,
                                                  int M, int N, int K, int ldk) {
    __shared__ __align__(16) u16 As[128 * 32];
    __shared__ __align__(16) u16 Bs[128 * 32];
    const int tid = threadIdx.x;
    const int wave = tid >> 6, lane = tid & 63;
    const int lhi = lane >> 4, llo = lane & 15;
    const int bx = blockIdx.x, by = blockIdx.y;
    const int kz = blockIdx.z * K;

    const int arow = wave * 32 + (lane >> 2);
    const int acol = (lane & 3) * 8;
    const u16* gA = A + (size_t)(by * 128 + arow) * ldk + kz + acol;
    const u16* gB = Bt + (size_t)(bx * 128 + arow) * ldk + kz + acol;
    u16* lA = As + wave * 1024 + lane * 8;
    u16* lB = Bs + wave * 1024 + lane * 8;

    const int wr = wave >> 1, wc = wave & 1;
    const f32x4 zero = {0.f, 0.f, 0.f, 0.f};
    f32x4 acc[4][4];
#pragma unroll
    for (int i = 0; i < 4; i++)
#pragma unroll
        for (int j = 0; j < 4; j++) acc[i][j] = zero;

    for (int k0 = 0; k0 < K; k0 += 32) {
        __syncthreads();
        gl_lds16(gA, lA);
        gl_lds16(gA + 16 * (size_t)ldk, lA + 512);
        gl_lds16(gB, lB);
        gl_lds16(gB + 16 * (size_t)ldk, lB + 512);
        gA += 32; gB += 32;
        __syncthreads();
        bf16x8 af[4], bfr[4];
#pragma unroll
        for (int i = 0; i < 4; i++)
            af[i] = *(const bf16x8*)(As + (wr * 64 + i * 16 + llo) * 32 + lhi * 8);
#pragma unroll
        for (int j = 0; j < 4; j++)
            bfr[j] = *(const bf16x8*)(Bs + (wc * 64 + j * 16 + llo) * 32 + lhi * 8);
#pragma unroll
        for (int i = 0; i < 4; i++)
#pragma unroll
            for (int j = 0; j < 4; j++)
                acc[i][j] = __builtin_amdgcn_mfma_f32_16x16x32_bf16(af[i], bfr[j], acc[i][j], 0, 0, 0);
    }

    const int rbase = by * 128 + wr * 64 + lhi * 4;
    const int cbase = bx * 128 + wc * 64 + llo;
    float* pout = nullptr;
    if constexpr (EPI == 4) {
        pout = (blockIdx.z < 2) ? ((float*)out0 + (size_t)blockIdx.z * M * N)
                                : ((float*)out1 + (size_t)(blockIdx.z - 2) * M * N);
    }
#pragma unroll
    for (int i = 0; i < 4; i++) {
#pragma unroll
        for (int j = 0; j < 4; j++) {
#pragma unroll
            for (int r = 0; r < 4; r++) {
                const int row = rbase + i * 16 + r;
                const int col = cbase + j * 16;
                float v = acc[i][j][r];
                if constexpr (EPI == 0) {
                    v += bias[col];
                    const int region = col >> 10;   // uniform per block
                    const int c = col & 1023;       // h*64 + t
                    const int b = row >> 11, n = row & 2047;
                    if (region == 0) {
                        ((float*)out0)[(size_t)row * 1024 + c] = v;  // Vsc f32
                    } else {
                        const int h = c >> 6, t = c & 63;
                        u16* dst = (region == 1) ? (u16*)out1 : (u16*)out2;
                        dst[(((size_t)(b * 16 + h)) * 2048 + n) * 64 + t] = f2bf(v);
                    }
                } else if constexpr (EPI == 2) {
                    v += bias[col];
                    v = v > 0.f ? v : 0.f;
                    ((u16*)out0)[(size_t)row * N + col] = f2bf(v);
                } else {
                    pout[(size_t)row * N + col] = v;
                }
            }
        }
    }
}

// ---------------- V transpose: Vsc f32 [B*N][1024] -> Vt bf16 [BH][64][2048] --
__global__ __launch_bounds__(256) void vtrans(const float* __restrict__ Vsc,
                                              u16* __restrict__ Vt) {
    __shared__ u16 Ts[64 * 72];
    const int nt = blockIdx.x;  // n-tile (0..31)
    const int bh = blockIdx.y;  // 0..31
    const int b = bh >> 4, h = bh & 15;
    const int t = threadIdx.x;
    const int n0 = nt * 64;
    const int nr = t >> 2;
    const int dq = (t & 3) * 16;
    const float* src = Vsc + ((size_t)(b * 2048 + n0 + nr)) * 1024 + h * 64 + dq;
    float4 v0 = ((const float4*)src)[0];
    float4 v1 = ((const float4*)src)[1];
    float4 v2 = ((const float4*)src)[2];
    float4 v3 = ((const float4*)src)[3];
    u16* c0 = Ts + nr;
    c0[(dq + 0) * 72]  = f2bf(v0.x); c0[(dq + 1) * 72]  = f2bf(v0.y);
    c0[(dq + 2) * 72]  = f2bf(v0.z); c0[(dq + 3) * 72]  = f2bf(v0.w);
    c0[(dq + 4) * 72]  = f2bf(v1.x); c0[(dq + 5) * 72]  = f2bf(v1.y);
    c0[(dq + 6) * 72]  = f2bf(v1.z); c0[(dq + 7) * 72]  = f2bf(v1.w);
    c0[(dq + 8) * 72]  = f2bf(v2.x); c0[(dq + 9) * 72]  = f2bf(v2.y);
    c0[(dq + 10) * 72] = f2bf(v2.z); c0[(dq + 11) * 72] = f2bf(v2.w);
    c0[(dq + 12) * 72] = f2bf(v3.x); c0[(dq + 13) * 72] = f2bf(v3.y);
    c0[(dq + 14) * 72] = f2bf(v3.z); c0[(dq + 15) * 72] = f2bf(v3.w);
    __syncthreads();
    const int d = t >> 2, n8 = (t & 3) * 16;
    bf16x8 o0 = *(const bf16x8*)(Ts + d * 72 + n8);
    bf16x8 o1 = *(const bf16x8*)(Ts + d * 72 + n8 + 8);
    u16* dst = Vt + ((size_t)bh * 64 + d) * 2048 + n0 + n8;
    *(bf16x8*)dst = o0;
    *(bf16x8*)(dst + 8) = o1;
}

// ---------------- staging helper for attn: K[64m][64d], V^T[64d][64m], swizzled ----
DEV void stage_kv(const u16* __restrict__ Kg, const u16* __restrict__ Vtg,
                  u16* ks, u16* vs, int bh, int m0, int wave, int lane) {
    const int l3 = lane >> 3, l7 = lane & 7;
    const int swcol = (l7 ^ l3) << 3;
#pragma unroll
    for (int s = 0; s < 2; s++) {
        const int row = wave * 16 + s * 8 + l3;
        gl_lds16(Kg + ((size_t)bh * 2048 + m0 + row) * 64 + swcol,
                 ks + wave * 1024 + s * 512 + lane * 8);
        gl_lds16(Vtg + ((size_t)bh * 64 + row) * 2048 + m0 + swcol,
                 vs + wave * 1024 + s * 512 + lane * 8);
    }
}

// ---------------- fused flash-style attention v5: 32x32 swapped-QK^T ----------------
// grid 1024, id = hh*64 + b*32 + qt. q-tile 64 (2 q-halves x 2 m-split waves),
// m-step 64 (two 32-chunks, one per wm), double-buffered LDS, 1 barrier/iter.
// S' = mfma(K, Q) -> lane holds S[m-reg][q=lane&31]; softmax fully in-register;
// P -> PV A-operand via cvt_pk_bf16 + lane^32 exchange (no Ps LDS round-trip).
__global__ __launch_bounds__(256, 4) void attn_fused5(const u16* __restrict__ Qg,
                                                      const u16* __restrict__ Kg,
                                                      const u16* __restrict__ Vtg,
                                                      const unsigned* __restrict__ Mp,
                                                      u16* __restrict__ attnL) {
    __shared__ __align__(16) u16 Ks[2][64 * 64];
    __shared__ __align__(16) u16 Vs[2][64 * 64];
    __shared__ float lsh[2][32], lsh2[2][32];
    const int tid = threadIdx.x, wave = tid >> 6, lane = tid & 63;
    const int qh = wave & 1, wm = wave >> 1;       // q-half, m-split
    const int hi = lane >> 5, l31 = lane & 31;
    const int id = blockIdx.x;
    const int hh = id >> 6, rem = id & 63;
    const int b = rem >> 5, qt = rem & 31;
    const int bh = b * 16 + hh;
    const int q0 = qt * 64;

    // prologue: stage tile 0; Q fragments direct to registers (held whole kernel)
    stage_kv(Kg, Vtg, Ks[0], Vs[0], bh, 0, wave, lane);
    const int qrow = q0 + qh * 32 + l31;
    const u16* qptr = Qg + ((size_t)bh * 2048 + qrow) * 64 + hi * 8;
    bf16x8 qf[4];
#pragma unroll
    for (int ks = 0; ks < 4; ks++) qf[ks] = *(const bf16x8*)(qptr + ks * 16);

    // permuted mask base: [b][mt][n][hi][reg], mt = 2t + wm
    const unsigned* mptr = Mp + (size_t)b * 4194304 + (size_t)wm * 65536
                              + (size_t)qrow * 32 + hi * 16;

    const f32x16 z16 = {0.f,0.f,0.f,0.f,0.f,0.f,0.f,0.f,0.f,0.f,0.f,0.f,0.f,0.f,0.f,0.f};
    f32x16 accO[2];
    accO[0] = z16; accO[1] = z16;
    float lsum = 0.f;
    const float CS = 0.125f * 1.4426950f;
    const bool h1 = (hi != 0);
    __syncthreads();

    for (int t = 0; t < 32; t++) {
        const int cur = t & 1;
        // mask loads FIRST (so their vmcnt wait doesn't drain the prefetch below)
        const uint4* mp4 = (const uint4*)(mptr + (size_t)t * 131072);
        const uint4 mva = mp4[0], mvb = mp4[1], mvc = mp4[2], mvd = mp4[3];
        // prefetch next tile into the other buffer; stays in flight through compute
        if (t < 31) stage_kv(Kg, Vtg, Ks[cur ^ 1], Vs[cur ^ 1], bh, (t + 1) * 64, wave, lane);

        // S'[m][q] = K·Q^T over d=64 (4 x mfma 32x32x16)
        const u16* ksb = Ks[cur];
        f32x16 sacc = z16;
        __builtin_amdgcn_s_setprio(1);
#pragma unroll
        for (int ks = 0; ks < 4; ks++) {
            const bf16x8 kf = *(const bf16x8*)(ksb + sw8(wm * 32 + l31, ks * 2 + hi));
            sacc = __builtin_amdgcn_mfma_f32_32x32x16_bf16(kf, qf[ks], sacc, 0, 0, 0);
        }
        __builtin_amdgcn_s_setprio(0);

        // softmax: lane owns q=l31; 16 m-values at m=(r&3)+8*(r>>2)+4*hi
        const unsigned mm[16] = {mva.x, mva.y, mva.z, mva.w, mvb.x, mvb.y, mvb.z, mvb.w,
                                 mvc.x, mvc.y, mvc.z, mvc.w, mvd.x, mvd.y, mvd.z, mvd.w};
        float p[16];
#pragma unroll
        for (int r = 0; r < 16; r++) {
            const unsigned u = mm[r];
            const float e = exp2f(fmaf(sacc[r], CS, __uint_as_float(u << 16)));
            lsum += e;
            p[r] = e * __uint_as_float(u & 0xFFFF0000u);
        }
        // pack pairs to bf16 and redistribute across lane^32 into PV A-fragments
        const unsigned w0 = cvtpk_bf16(p[0], p[1]),   w1 = cvtpk_bf16(p[2], p[3]);
        const unsigned w2 = cvtpk_bf16(p[4], p[5]),   w3 = cvtpk_bf16(p[6], p[7]);
        const unsigned w4 = cvtpk_bf16(p[8], p[9]),   w5 = cvtpk_bf16(p[10], p[11]);
        const unsigned w6 = cvtpk_bf16(p[12], p[13]), w7 = cvtpk_bf16(p[14], p[15]);
        const unsigned o0 = (unsigned)__shfl_xor((int)w0, 32);
        const unsigned o1 = (unsigned)__shfl_xor((int)w1, 32);
        const unsigned o2 = (unsigned)__shfl_xor((int)w2, 32);
        const unsigned o3 = (unsigned)__shfl_xor((int)w3, 32);
        const unsigned o4 = (unsigned)__shfl_xor((int)w4, 32);
        const unsigned o5 = (unsigned)__shfl_xor((int)w5, 32);
        const unsigned o6 = (unsigned)__shfl_xor((int)w6, 32);
        const unsigned o7 = (unsigned)__shfl_xor((int)w7, 32);
        const u32x4 fa0 = {h1 ? o2 : w0, h1 ? o3 : w1, h1 ? w2 : o0, h1 ? w3 : o1};
        const u32x4 fa1 = {h1 ? o6 : w4, h1 ? o7 : w5, h1 ? w6 : o4, h1 ? w7 : o5};
        const bf16x8 pa0 = __builtin_bit_cast(bf16x8, fa0);
        const bf16x8 pa1 = __builtin_bit_cast(bf16x8, fa1);

        // O[q][d] += P @ V  (2 k-steps of 16 m x 2 d-halves)
        const u16* vsb = Vs[cur];
        __builtin_amdgcn_s_setprio(1);
#pragma unroll
        for (int dh = 0; dh < 2; dh++) {
            const bf16x8 vf0 = *(const bf16x8*)(vsb + sw8(dh * 32 + l31, wm * 4 + hi));
            accO[dh] = __builtin_amdgcn_mfma_f32_32x32x16_bf16(pa0, vf0, accO[dh], 0, 0, 0);
            const bf16x8 vf1 = *(const bf16x8*)(vsb + sw8(dh * 32 + l31, wm * 4 + 2 + hi));
            accO[dh] = __builtin_amdgcn_mfma_f32_32x32x16_bf16(pa1, vf1, accO[dh], 0, 0, 0);
        }
        __builtin_amdgcn_s_setprio(0);
        __syncthreads();
    }

    // combine the wm pair (same qh), then epilogue by wm=0 waves
    const float lsum2 = lsum + __shfl_xor(lsum, 32);
    float* cb = (float*)&Ks[0][0];   // 16 KB: 2 qh x 64 lanes x 32 floats
    if (wm == 1) {
        float* dst = cb + (size_t)(qh * 64 + lane) * 32;
#pragma unroll
        for (int dh = 0; dh < 2; dh++)
#pragma unroll
            for (int c = 0; c < 4; c++) {
                const f32x4 v = {accO[dh][c * 4 + 0], accO[dh][c * 4 + 1],
                                 accO[dh][c * 4 + 2], accO[dh][c * 4 + 3]};
                *(f32x4*)(dst + dh * 16 + c * 4) = v;
            }
        if (lane < 32) lsh[qh][lane] = lsum2;
    }
    __syncthreads();
    if (wm == 0) {
        const float* src = cb + (size_t)(qh * 64 + lane) * 32;
        const float lt = lsum2 + lsh[qh][l31];
#pragma unroll
        for (int dh = 0; dh < 2; dh++)
#pragma unroll
            for (int c = 0; c < 16; c++)
                accO[dh][c] += src[dh * 16 + c];
        if (lane < 32) lsh2[qh][lane] = 1.0f / lt;
    }
    __syncthreads();
    if (wm == 0) {
#pragma unroll
        for (int r = 0; r < 16; r++) {
            const int ql = (r & 3) + 8 * (r >> 2) + 4 * hi;
            const float linv = lsh2[qh][ql];
            const int qg = q0 + qh * 32 + ql;
#pragma unroll
            for (int dh = 0; dh < 2; dh++) {
                float v = accO[dh][r] * linv;
                v = v >= 0.f ? v : 0.01f * v;
                attnL[((size_t)b * 2048 + qg) * 1024 + hh * 64 + dh * 32 + l31] = f2bf(v);
            }
        }
    }
}

// ---------------- launcher ----------------
extern "C" void kernel_launch(void* const* d_in, const int* in_sizes, int n_in,
                              void* d_out, int out_size, void* d_ws, size_t ws_size,
                              hipStream_t stream) {
    const float* Z     = (const float*)d_in[0];
    const float* nmask = (const float*)d_in[1];
    const float* pmask = (const float*)d_in[2];
    const float* ln1_g = (const float*)d_in[3];
    const float* ln1_b = (const float*)d_in[4];
    const float* qkv_w = (const float*)d_in[5];
    const float* qkv_b = (const float*)d_in[6];
    const float* o_w   = (const float*)d_in[7];
    const float* ln2_g = (const float*)d_in[8];
    const float* ln2_b = (const float*)d_in[9];
    const float* p1_w  = (const float*)d_in[10];
    const float* p1_b  = (const float*)d_in[11];
    const float* p2_w  = (const float*)d_in[12];
    const float* p2_b  = (const float*)d_in[13];
    float* out = (float*)d_out;

    char* w = (char*)d_ws;
    auto take = [&](size_t bytes) -> char* {
        char* p = w;
        w += (bytes + 255) & ~(size_t)255;
        return p;
    };
    u16* qkvW   = (u16*)take((size_t)3072 * 1024 * 2);
    u16* oW     = (u16*)take((size_t)1024 * 1024 * 2);
    u16* p1W    = (u16*)take((size_t)4096 * 1024 * 2);
    u16* p2W    = (u16*)take((size_t)1024 * 4096 * 2);
    u16* Zn     = (u16*)take((size_t)4096 * 1024 * 2);   // reused for Zn2
    u16* Qb     = (u16*)take((size_t)32 * 2048 * 64 * 2);
    u16* Kb     = (u16*)take((size_t)32 * 2048 * 64 * 2);
    u16* Vt     = (u16*)take((size_t)32 * 64 * 2048 * 2);
    u16* attnL  = (u16*)take((size_t)4096 * 1024 * 2);
    float* Z1   = (float*)take((size_t)4096 * 1024 * 4);
    u16* hbuf   = (u16*)take((size_t)4096 * 4096 * 2);   // 33.55 MB
    unsigned* Mp = (unsigned*)take((size_t)2 * 2048 * 2048 * 4);  // 33.55 MB
    float* pbias = (float*)take((size_t)3072 * 4);
    float* Vsc    = (float*)hbuf;          // alias: dead before hbuf written
    float* part01 = (float*)Mp;            // alias: Mp dead after attention
    float* part23 = (float*)hbuf;          // alias: hbuf dead during o-proj

    // merged prep (casts + bias permute + mask pack)
    prep_all<<<dim3(20481), 256, 0, stream>>>(qkv_w, o_w, p1_w, p2_w, qkv_b, nmask, pmask,
                                              qkvW, oW, p1W, p2W, pbias, Mp);
    // LN1
    ln_bf16<<<dim3(4096), 256, 0, stream>>>(Z, ln1_g, ln1_b, Zn);
    // QKV projection: V -> f32 scratch, Q/K -> bf16 [BH][N][64]
    gemm_bt<0><<<dim3(24, 32), 256, 0, stream>>>(Zn, qkvW, pbias, Vsc, Qb, Kb, 4096, 3072, 1024, 1024);
    // V transpose -> Vt [BH][64][2048]
    vtrans<<<dim3(32, 32), 256, 0, stream>>>(Vsc, Vt);
    // attention (4 blocks/CU, 32x32 swapped-QK^T, in-register softmax)
    attn_fused5<<<dim3(1024), 256, 0, stream>>>(Qb, Kb, Vt, Mp, attnL);
    // o-projection, split-K=4 -> f32 partials (p0,p1 in Mp; p2,p3 in hbuf)
    gemm_bt<4><<<dim3(8, 32, 4), 256, 0, stream>>>(attnL, oW, nullptr, part01, part23, nullptr,
                                                   4096, 1024, 256, 1024);
    // 4-way combine + residual + LN2 (writes Z1 and Zn)
    ln2_comb4<<<dim3(4096), 256, 0, stream>>>(part01, part01 + (size_t)4096 * 1024,
                                              part23, part23 + (size_t)4096 * 1024,
                                              Z, ln2_g, ln2_b, Z1, Zn);
    // MLP up + relu -> hbuf (bf16)
    gemm_bt<2><<<dim3(32, 32), 256, 0, stream>>>(Zn, p1W, p1_b, hbuf, nullptr, nullptr,
                                                 4096, 4096, 1024, 1024);
    // MLP down, split-K=2 -> f32 partials in Mp
    gemm_bt<4><<<dim3(8, 32, 2), 256, 0, stream>>>(hbuf, p2W, nullptr, part01, nullptr, nullptr,
                                                   4096, 1024, 2048, 4096);
    // final combine -> out
    out_comb<<<dim3(4096), 256, 0, stream>>>(part01, part01 + (size_t)4096 * 1024, p2_b, Z1, out);
}

// Round 2
// 447.788 us; speedup vs baseline: 1.0245x; 1.0245x over previous
//
#include <hip/hip_runtime.h>

typedef unsigned short u16;
typedef __attribute__((ext_vector_type(8))) short bf16x8;
typedef __attribute__((ext_vector_type(4))) float f32x4;
typedef __attribute__((ext_vector_type(16))) float f32x16;
typedef __attribute__((ext_vector_type(4))) unsigned u32x4;

#define DEV static __device__ __forceinline__

DEV u16 f2bf(float f) {
    unsigned u = __float_as_uint(f);
    u += 0x7FFFu + ((u >> 16) & 1u);
    return (u16)(u >> 16);
}

typedef const __attribute__((address_space(1))) void* gas1_t;
typedef __attribute__((address_space(3))) void* gas3_t;

DEV void gl_lds16(const u16* g, u16* l) {
    __builtin_amdgcn_global_load_lds((gas1_t)g, (gas3_t)l, 16, 0, 0);
}

DEV unsigned cvtpk_bf16(float a, float b) {
    unsigned r;
    asm("v_cvt_pk_bf16_f32 %0, %1, %2" : "=v"(r) : "v"(a), "v"(b));
    return r;
}

// swizzled LDS offset (u16 units) for 128B rows of 64 u16, 16B chunks
DEV int sw8(int row, int chunk) { return row * 64 + ((chunk ^ (row & 7)) << 3); }

// ---------------- merged prep: weight casts + bias permute + mask pack ----------------
// block ranges: [0,3072) qkvW | [3072,4096) oW | [4096,8192) p1W | [8192,12288) p2W
//               | [12288,20480) mask pack | 20480 pbias
__global__ __launch_bounds__(256) void prep_all(const float* __restrict__ qkv_w,
                                                const float* __restrict__ o_w,
                                                const float* __restrict__ p1_w,
                                                const float* __restrict__ p2_w,
                                                const float* __restrict__ qkv_b,
                                                const float* __restrict__ nm,
                                                const float* __restrict__ pm,
                                                u16* __restrict__ qkvW,
                                                u16* __restrict__ oW,
                                                u16* __restrict__ p1W,
                                                u16* __restrict__ p2W,
                                                float* __restrict__ pbias,
                                                unsigned* __restrict__ Mp) {
    const int bid = blockIdx.x, t = threadIdx.x;
    if (bid < 3072) {            // qkv cast + row permute: rows = [V|Q|K], each h*64+t
        int i = bid * 256 + t;
        int orow = i >> 8, cc = i & 255;
        int region = orow >> 10, rem = orow & 1023, h = rem >> 6, tt = rem & 63;
        int srow = h * 192 + region * 64 + tt;
        float4 v = ((const float4*)qkv_w)[srow * 256 + cc];
        ushort4 o;
        o.x = f2bf(v.x); o.y = f2bf(v.y); o.z = f2bf(v.z); o.w = f2bf(v.w);
        ((ushort4*)qkvW)[i] = o;
    } else if (bid < 4096) {     // o_w cast
        int i = (bid - 3072) * 256 + t;
        float4 v = ((const float4*)o_w)[i];
        ushort4 o;
        o.x = f2bf(v.x); o.y = f2bf(v.y); o.z = f2bf(v.z); o.w = f2bf(v.w);
        ((ushort4*)oW)[i] = o;
    } else if (bid < 8192) {     // p1_w cast
        int i = (bid - 4096) * 256 + t;
        float4 v = ((const float4*)p1_w)[i];
        ushort4 o;
        o.x = f2bf(v.x); o.y = f2bf(v.y); o.z = f2bf(v.z); o.w = f2bf(v.w);
        ((ushort4*)p1W)[i] = o;
    } else if (bid < 12288) {    // p2_w cast
        int i = (bid - 8192) * 256 + t;
        float4 v = ((const float4*)p2_w)[i];
        ushort4 o;
        o.x = f2bf(v.x); o.y = f2bf(v.y); o.z = f2bf(v.z); o.w = f2bf(v.w);
        ((ushort4*)p2W)[i] = o;
    } else if (bid < 20480) {    // mask pack, coalesced layout [b][mt][c][n][hi]
        int i = (bid - 12288) * 256 + t;           // uint4 index; 4 consecutive m
        float4 a = ((const float4*)nm)[i];
        float4 b = ((const float4*)pm)[i];
        uint4 o;
        o.x = ((unsigned)f2bf(b.x) << 16) | f2bf(a.x * 1.4426950f);
        o.y = ((unsigned)f2bf(b.y) << 16) | f2bf(a.y * 1.4426950f);
        o.z = ((unsigned)f2bf(b.z) << 16) | f2bf(a.z * 1.4426950f);
        o.w = ((unsigned)f2bf(b.w) << 16) | f2bf(a.w * 1.4426950f);
        // 4 consecutive m (same quad) -> regs r=4c..4c+3 of lane half hi:
        // m5 = (r&3) + 8*(r>>2) + 4*hi  =>  c = (m&31)>>3, hi = (m>>2)&1
        int e = i * 4;
        int bb = e >> 22;
        int rem = e & 4194303;
        int n = rem >> 11;
        int m = rem & 2047;
        int mt = m >> 5;
        int m5 = m & 31;
        int c = m5 >> 3;
        int hi = (m5 >> 2) & 1;
        size_t oi = (((size_t)(bb * 64 + mt) * 4 + c) * 2048 + n) * 2 + hi;
        ((uint4*)Mp)[oi] = o;
    } else {                     // qkv bias permute (3072 elements)
#pragma unroll
        for (int k = 0; k < 12; k++) {
            int i = k * 256 + t;
            int region = i >> 10, rem = i & 1023, h = rem >> 6, tt = rem & 63;
            pbias[i] = qkv_b[h * 192 + region * 64 + tt];
        }
    }
}

// ---------------- LayerNorm (D=1024) f32 -> bf16 ----------------
__global__ __launch_bounds__(256) void ln_bf16(const float* __restrict__ x,
                                               const float* __restrict__ gam,
                                               const float* __restrict__ bet,
                                               u16* __restrict__ y) {
    const int row = blockIdx.x;
    const int t = threadIdx.x;
    const float4 v = ((const float4*)(x + (size_t)row * 1024))[t];
    float s = v.x + v.y + v.z + v.w;
    float ss = v.x * v.x + v.y * v.y + v.z * v.z + v.w * v.w;
#pragma unroll
    for (int o = 1; o < 64; o <<= 1) {
        s += __shfl_xor(s, o);
        ss += __shfl_xor(ss, o);
    }
    __shared__ float rs[4], rss[4];
    const int wave = t >> 6, lane = t & 63;
    if (lane == 0) { rs[wave] = s; rss[wave] = ss; }
    __syncthreads();
    const float tot = rs[0] + rs[1] + rs[2] + rs[3];
    const float totss = rss[0] + rss[1] + rss[2] + rss[3];
    const float mu = tot * (1.0f / 1024.0f);
    const float var = totss * (1.0f / 1024.0f) - mu * mu;
    const float rstd = rsqrtf(var + 1e-5f);
    const float4 g4 = ((const float4*)gam)[t];
    const float4 b4 = ((const float4*)bet)[t];
    ushort4 o;
    o.x = f2bf((v.x - mu) * rstd * g4.x + b4.x);
    o.y = f2bf((v.y - mu) * rstd * g4.y + b4.y);
    o.z = f2bf((v.z - mu) * rstd * g4.z + b4.z);
    o.w = f2bf((v.w - mu) * rstd * g4.w + b4.w);
    ((ushort4*)(y + (size_t)row * 1024))[t] = o;
}

// ---- fused 4-way combine + residual + LayerNorm ----
__global__ __launch_bounds__(256) void ln2_comb4(const float* __restrict__ p0,
                                                 const float* __restrict__ p1,
                                                 const float* __restrict__ p2,
                                                 const float* __restrict__ p3,
                                                 const float* __restrict__ Z,
                                                 const float* __restrict__ gam,
                                                 const float* __restrict__ bet,
                                                 float* __restrict__ Z1,
                                                 u16* __restrict__ y) {
    const int row = blockIdx.x;
    const int t = threadIdx.x;
    const size_t off = (size_t)row * 256 + t;
    const float4 a = ((const float4*)p0)[off];
    const float4 c = ((const float4*)p1)[off];
    const float4 d = ((const float4*)p2)[off];
    const float4 e = ((const float4*)p3)[off];
    const float4 z = ((const float4*)Z)[off];
    float4 v;
    v.x = a.x + c.x + d.x + e.x + z.x;
    v.y = a.y + c.y + d.y + e.y + z.y;
    v.z = a.z + c.z + d.z + e.z + z.z;
    v.w = a.w + c.w + d.w + e.w + z.w;
    ((float4*)Z1)[off] = v;
    float s = v.x + v.y + v.z + v.w;
    float ss = v.x * v.x + v.y * v.y + v.z * v.z + v.w * v.w;
#pragma unroll
    for (int o = 1; o < 64; o <<= 1) {
        s += __shfl_xor(s, o);
        ss += __shfl_xor(ss, o);
    }
    __shared__ float rs[4], rss[4];
    const int wave = t >> 6, lane = t & 63;
    if (lane == 0) { rs[wave] = s; rss[wave] = ss; }
    __syncthreads();
    const float tot = rs[0] + rs[1] + rs[2] + rs[3];
    const float totss = rss[0] + rss[1] + rss[2] + rss[3];
    const float mu = tot * (1.0f / 1024.0f);
    const float var = totss * (1.0f / 1024.0f) - mu * mu;
    const float rstd = rsqrtf(var + 1e-5f);
    const float4 g4 = ((const float4*)gam)[t];
    const float4 b4 = ((const float4*)bet)[t];
    ushort4 o;
    o.x = f2bf((v.x - mu) * rstd * g4.x + b4.x);
    o.y = f2bf((v.y - mu) * rstd * g4.y + b4.y);
    o.z = f2bf((v.z - mu) * rstd * g4.z + b4.z);
    o.w = f2bf((v.w - mu) * rstd * g4.w + b4.w);
    ((ushort4*)(y + (size_t)row * 1024))[t] = o;
}

// ---- final combine: out = p0 + p1 + bias + Z1 ----
__global__ __launch_bounds__(256) void out_comb(const float* __restrict__ p0,
                                                const float* __restrict__ p1,
                                                const float* __restrict__ bias,
                                                const float* __restrict__ Z1,
                                                float* __restrict__ out) {
    int i = blockIdx.x * 256 + threadIdx.x;   // 1048576 float4s
    float4 a = ((const float4*)p0)[i];
    float4 c = ((const float4*)p1)[i];
    float4 z = ((const float4*)Z1)[i];
    float4 b = ((const float4*)bias)[i & 255];
    float4 o;
    o.x = a.x + c.x + z.x + b.x; o.y = a.y + c.y + z.y + b.y;
    o.z = a.z + c.z + z.z + b.z; o.w = a.w + c.w + z.w + b.w;
    ((float4*)out)[i] = o;
}

// ---------------- GEMM: C[M,N] = A[M,K-slice] @ Bt[N,K-slice]^T ----------------
// 128x128 tile, BK=32. ldk = row stride; K = slice length; slice start = z*K.
// EPI 0: +pbias; region: 0 -> f32 Vsc(out0), 1 -> Q bf16(out1), 2 -> K bf16(out2)
// EPI 2: +bias, relu, write bf16 out0
// EPI 4: raw f32 partial -> (z<2 ? out0 : out1) + (z&1)*M*N
template <int EPI>
__global__ __launch_bounds__(256, 3) void gemm_bt(const u16* __restrict__ A,
                                                  const u16* __restrict__ Bt,
                                                  const float* __restrict__ bias,
                                                  void* __restrict__ out0,
                                                  void* __restrict__ out1,
                                                  void* __restrict__ out2,
                                                  int M, int N, int K, int ldk) {
    __shared__ __align__(16) u16 As[128 * 32];
    __shared__ __align__(16) u16 Bs[128 * 32];
    const int tid = threadIdx.x;
    const int wave = tid >> 6, lane = tid & 63;
    const int lhi = lane >> 4, llo = lane & 15;
    const int bx = blockIdx.x, by = blockIdx.y;
    const int kz = blockIdx.z * K;

    const int arow = wave * 32 + (lane >> 2);
    const int acol = (lane & 3) * 8;
    const u16* gA = A + (size_t)(by * 128 + arow) * ldk + kz + acol;
    const u16* gB = Bt + (size_t)(bx * 128 + arow) * ldk + kz + acol;
    u16* lA = As + wave * 1024 + lane * 8;
    u16* lB = Bs + wave * 1024 + lane * 8;

    const int wr = wave >> 1, wc = wave & 1;
    const f32x4 zero = {0.f, 0.f, 0.f, 0.f};
    f32x4 acc[4][4];
#pragma unroll
    for (int i = 0; i < 4; i++)
#pragma unroll
        for (int j = 0; j < 4; j++) acc[i][j] = zero;

    for (int k0 = 0; k0 < K; k0 += 32) {
        __syncthreads();
        gl_lds16(gA, lA);
        gl_lds16(gA + 16 * (size_t)ldk, lA + 512);
        gl_lds16(gB, lB);
        gl_lds16(gB + 16 * (size_t)ldk, lB + 512);
        gA += 32; gB += 32;
        __syncthreads();
        bf16x8 af[4], bfr[4];
#pragma unroll
        for (int i = 0; i < 4; i++)
            af[i] = *(const bf16x8*)(As + (wr * 64 + i * 16 + llo) * 32 + lhi * 8);
#pragma unroll
        for (int j = 0; j < 4; j++)
            bfr[j] = *(const bf16x8*)(Bs + (wc * 64 + j * 16 + llo) * 32 + lhi * 8);
#pragma unroll
        for (int i = 0; i < 4; i++)
#pragma unroll
            for (int j = 0; j < 4; j++)
                acc[i][j] = __builtin_amdgcn_mfma_f32_16x16x32_bf16(af[i], bfr[j], acc[i][j], 0, 0, 0);
    }

    const int rbase = by * 128 + wr * 64 + lhi * 4;
    const int cbase = bx * 128 + wc * 64 + llo;
    float* pout = nullptr;
    if constexpr (EPI == 4) {
        pout = (blockIdx.z < 2) ? ((float*)out0 + (size_t)blockIdx.z * M * N)
                                : ((float*)out1 + (size_t)(blockIdx.z - 2) * M * N);
    }
#pragma unroll
    for (int i = 0; i < 4; i++) {
#pragma unroll
        for (int j = 0; j < 4; j++) {
#pragma unroll
            for (int r = 0; r < 4; r++) {
                const int row = rbase + i * 16 + r;
                const int col = cbase + j * 16;
                float v = acc[i][j][r];
                if constexpr (EPI == 0) {
                    v += bias[col];
                    const int region = col >> 10;   // uniform per block
                    const int c = col & 1023;       // h*64 + t
                    const int b = row >> 11, n = row & 2047;
                    if (region == 0) {
                        ((float*)out0)[(size_t)row * 1024 + c] = v;  // Vsc f32
                    } else {
                        const int h = c >> 6, t = c & 63;
                        u16* dst = (region == 1) ? (u16*)out1 : (u16*)out2;
                        dst[(((size_t)(b * 16 + h)) * 2048 + n) * 64 + t] = f2bf(v);
                    }
                } else if constexpr (EPI == 2) {
                    v += bias[col];
                    v = v > 0.f ? v : 0.f;
                    ((u16*)out0)[(size_t)row * N + col] = f2bf(v);
                } else {
                    pout[(size_t)row * N + col] = v;
                }
            }
        }
    }
}

// ---------------- V transpose: Vsc f32 [B*N][1024] -> Vt bf16 [BH][64][2048] --
// m-columns written in PV k-order: within each 32-block, pos-group of m-group
// (bits b4b3b2 of m&31) is b4*4 + b2*2 + b3 (swap low two group bits).
__global__ __launch_bounds__(256) void vtrans(const float* __restrict__ Vsc,
                                              u16* __restrict__ Vt) {
    __shared__ u16 Ts[64 * 72];
    const int nt = blockIdx.x;  // n-tile (0..31)
    const int bh = blockIdx.y;  // 0..31
    const int b = bh >> 4, h = bh & 15;
    const int t = threadIdx.x;
    const int n0 = nt * 64;
    const int nr = t >> 2;
    const int dq = (t & 3) * 16;
    const float* src = Vsc + ((size_t)(b * 2048 + n0 + nr)) * 1024 + h * 64 + dq;
    float4 v0 = ((const float4*)src)[0];
    float4 v1 = ((const float4*)src)[1];
    float4 v2 = ((const float4*)src)[2];
    float4 v3 = ((const float4*)src)[3];
    u16* c0 = Ts + nr;
    c0[(dq + 0) * 72]  = f2bf(v0.x); c0[(dq + 1) * 72]  = f2bf(v0.y);
    c0[(dq + 2) * 72]  = f2bf(v0.z); c0[(dq + 3) * 72]  = f2bf(v0.w);
    c0[(dq + 4) * 72]  = f2bf(v1.x); c0[(dq + 5) * 72]  = f2bf(v1.y);
    c0[(dq + 6) * 72]  = f2bf(v1.z); c0[(dq + 7) * 72]  = f2bf(v1.w);
    c0[(dq + 8) * 72]  = f2bf(v2.x); c0[(dq + 9) * 72]  = f2bf(v2.y);
    c0[(dq + 10) * 72] = f2bf(v2.z); c0[(dq + 11) * 72] = f2bf(v2.w);
    c0[(dq + 12) * 72] = f2bf(v3.x); c0[(dq + 13) * 72] = f2bf(v3.y);
    c0[(dq + 14) * 72] = f2bf(v3.z); c0[(dq + 15) * 72] = f2bf(v3.w);
    __syncthreads();
    const int d = t >> 2, n8 = (t & 3) * 16;
    u16* dstrow = Vt + ((size_t)bh * 64 + d) * 2048 + n0;
#pragma unroll
    for (int w = 0; w < 4; w++) {
        const int gi = (n8 >> 2) + w;          // m-group id within 64-tile
        const int g5 = gi & 7, blk = gi >> 3;
        const int pg = (g5 & 4) | ((g5 & 1) << 1) | ((g5 >> 1) & 1);
        *(uint2*)(dstrow + blk * 32 + pg * 4) = *(const uint2*)(Ts + d * 72 + n8 + w * 4);
    }
}

// ---------------- staging helper for attn: K[64m][64d], V^T[64d][64m], swizzled ----
DEV void stage_kv(const u16* __restrict__ Kg, const u16* __restrict__ Vtg,
                  u16* ks, u16* vs, int bh, int m0, int wave, int lane) {
    const int l3 = lane >> 3, l7 = lane & 7;
    const int swcol = (l7 ^ l3) << 3;
#pragma unroll
    for (int s = 0; s < 2; s++) {
        const int row = wave * 16 + s * 8 + l3;
        gl_lds16(Kg + ((size_t)bh * 2048 + m0 + row) * 64 + swcol,
                 ks + wave * 1024 + s * 512 + lane * 8);
        gl_lds16(Vtg + ((size_t)bh * 64 + row) * 2048 + m0 + swcol,
                 vs + wave * 1024 + s * 512 + lane * 8);
    }
}

// ---------------- fused flash-style attention v6 ----------------
// 32x32 swapped-QK^T, in-register softmax, NO cross-lane P exchange (V columns
// pre-permuted to register k-order), coalesced permuted masks, XCD-grouped grid
// (all 16 heads of a (b,q-tile) group on one XCD -> mask re-reads hit L2).
__global__ __launch_bounds__(256, 4) void attn_fused6(const u16* __restrict__ Qg,
                                                      const u16* __restrict__ Kg,
                                                      const u16* __restrict__ Vtg,
                                                      const unsigned* __restrict__ Mp,
                                                      u16* __restrict__ attnL) {
    __shared__ __align__(16) u16 Ks[2][64 * 64];
    __shared__ __align__(16) u16 Vs[2][64 * 64];
    __shared__ float lsh[2][32], lsh2[2][32];
    const int tid = threadIdx.x, wave = tid >> 6, lane = tid & 63;
    const int qh = wave & 1, wm = wave >> 1;       // q-half, m-split
    const int hi = lane >> 5, l31 = lane & 31;
    // XCD-grouped block decode: 16 heads of a group land on one XCD, adjacent in time
    const int pid = blockIdx.x;
    const int seq = pid >> 3;
    const int hh = seq & 15;
    const int g = (pid & 7) + (seq >> 4) * 8;      // 0..63 = b*32 + qt
    const int b = g >> 5, qt = g & 31;
    const int bh = b * 16 + hh;
    const int q0 = qt * 64;

    // prologue: stage tile 0; Q fragments direct to registers (held whole kernel)
    stage_kv(Kg, Vtg, Ks[0], Vs[0], bh, 0, wave, lane);
    const int qrow = q0 + qh * 32 + l31;
    const u16* qptr = Qg + ((size_t)bh * 2048 + qrow) * 64 + hi * 8;
    bf16x8 qf[4];
#pragma unroll
    for (int ks = 0; ks < 4; ks++) qf[ks] = *(const bf16x8*)(qptr + ks * 16);

    // coalesced mask base: layout [b][mt][c][n][hi] (uint4 units), mt = 2t + wm
    const uint4* mb4 = (const uint4*)Mp + ((size_t)(b * 64 + wm) * 4) * 4096
                                        + (size_t)qrow * 2 + hi;

    const f32x16 z16 = {0.f,0.f,0.f,0.f,0.f,0.f,0.f,0.f,0.f,0.f,0.f,0.f,0.f,0.f,0.f,0.f};
    f32x16 accO[2];
    accO[0] = z16; accO[1] = z16;
    float lsum = 0.f;
    const float CS = 0.125f * 1.4426950f;
    __syncthreads();

    for (int t = 0; t < 32; t++) {
        const int cur = t & 1;
        // mask loads FIRST (each is one fully-coalesced 1KB wave transaction);
        // the softmax's vmcnt wait then leaves the prefetch below in flight
        const uint4* mp4 = mb4 + (size_t)t * 32768;
        const uint4 mva = mp4[0], mvb = mp4[4096], mvc = mp4[8192], mvd = mp4[12288];
        // prefetch next tile into the other buffer; stays in flight through compute
        if (t < 31) stage_kv(Kg, Vtg, Ks[cur ^ 1], Vs[cur ^ 1], bh, (t + 1) * 64, wave, lane);

        // S'[m][q] = K·Q^T over d=64 (4 x mfma 32x32x16)
        const u16* ksb = Ks[cur];
        f32x16 sacc = z16;
        __builtin_amdgcn_s_setprio(1);
#pragma unroll
        for (int ks = 0; ks < 4; ks++) {
            const bf16x8 kf = *(const bf16x8*)(ksb + sw8(wm * 32 + l31, ks * 2 + hi));
            sacc = __builtin_amdgcn_mfma_f32_32x32x16_bf16(kf, qf[ks], sacc, 0, 0, 0);
        }
        __builtin_amdgcn_s_setprio(0);

        // softmax: lane owns q=l31; 16 m-values at m=(r&3)+8*(r>>2)+4*hi
        const unsigned mm[16] = {mva.x, mva.y, mva.z, mva.w, mvb.x, mvb.y, mvb.z, mvb.w,
                                 mvc.x, mvc.y, mvc.z, mvc.w, mvd.x, mvd.y, mvd.z, mvd.w};
        float p[16];
#pragma unroll
        for (int r = 0; r < 16; r++) {
            const unsigned u = mm[r];
            const float e = exp2f(fmaf(sacc[r], CS, __uint_as_float(u << 16)));
            lsum += e;
            p[r] = e * __uint_as_float(u & 0xFFFF0000u);
        }
        // PV A-fragments = own registers in order (V columns pre-permuted to match)
        const u32x4 fa0 = {cvtpk_bf16(p[0], p[1]),  cvtpk_bf16(p[2], p[3]),
                           cvtpk_bf16(p[4], p[5]),  cvtpk_bf16(p[6], p[7])};
        const u32x4 fa1 = {cvtpk_bf16(p[8], p[9]),  cvtpk_bf16(p[10], p[11]),
                           cvtpk_bf16(p[12], p[13]), cvtpk_bf16(p[14], p[15])};
        const bf16x8 pa0 = __builtin_bit_cast(bf16x8, fa0);
        const bf16x8 pa1 = __builtin_bit_cast(bf16x8, fa1);

        // O[q][d] += P @ V  (2 k-steps of 16 m x 2 d-halves)
        const u16* vsb = Vs[cur];
        __builtin_amdgcn_s_setprio(1);
#pragma unroll
        for (int dh = 0; dh < 2; dh++) {
            const bf16x8 vf0 = *(const bf16x8*)(vsb + sw8(dh * 32 + l31, wm * 4 + hi));
            accO[dh] = __builtin_amdgcn_mfma_f32_32x32x16_bf16(pa0, vf0, accO[dh], 0, 0, 0);
            const bf16x8 vf1 = *(const bf16x8*)(vsb + sw8(dh * 32 + l31, wm * 4 + 2 + hi));
            accO[dh] = __builtin_amdgcn_mfma_f32_32x32x16_bf16(pa1, vf1, accO[dh], 0, 0, 0);
        }
        __builtin_amdgcn_s_setprio(0);
        __syncthreads();
    }

    // combine the wm pair (same qh), then epilogue by wm=0 waves
    const float lsum2 = lsum + __shfl_xor(lsum, 32);
    float* cb = (float*)&Ks[0][0];   // 16 KB: 2 qh x 64 lanes x 32 floats
    if (wm == 1) {
        float* dst = cb + (size_t)(qh * 64 + lane) * 32;
#pragma unroll
        for (int dh = 0; dh < 2; dh++)
#pragma unroll
            for (int c = 0; c < 4; c++) {
                const f32x4 v = {accO[dh][c * 4 + 0], accO[dh][c * 4 + 1],
                                 accO[dh][c * 4 + 2], accO[dh][c * 4 + 3]};
                *(f32x4*)(dst + dh * 16 + c * 4) = v;
            }
        if (lane < 32) lsh[qh][lane] = lsum2;
    }
    __syncthreads();
    if (wm == 0) {
        const float* src = cb + (size_t)(qh * 64 + lane) * 32;
        const float lt = lsum2 + lsh[qh][l31];
#pragma unroll
        for (int dh = 0; dh < 2; dh++)
#pragma unroll
            for (int c = 0; c < 16; c++)
                accO[dh][c] += src[dh * 16 + c];
        if (lane < 32) lsh2[qh][lane] = 1.0f / lt;
    }
    __syncthreads();
    if (wm == 0) {
#pragma unroll
        for (int r = 0; r < 16; r++) {
            const int ql = (r & 3) + 8 * (r >> 2) + 4 * hi;
            const float linv = lsh2[qh][ql];
            const int qg = q0 + qh * 32 + ql;
#pragma unroll
            for (int dh = 0; dh < 2; dh++) {
                float v = accO[dh][r] * linv;
                v = v >= 0.f ? v : 0.01f * v;
                attnL[((size_t)b * 2048 + qg) * 1024 + hh * 64 + dh * 32 + l31] = f2bf(v);
            }
        }
    }
}

// ---------------- launcher ----------------
extern "C" void kernel_launch(void* const* d_in, const int* in_sizes, int n_in,
                              void* d_out, int out_size, void* d_ws, size_t ws_size,
                              hipStream_t stream) {
    const float* Z     = (const float*)d_in[0];
    const float* nmask = (const float*)d_in[1];
    const float* pmask = (const float*)d_in[2];
    const float* ln1_g = (const float*)d_in[3];
    const float* ln1_b = (const float*)d_in[4];
    const float* qkv_w = (const float*)d_in[5];
    const float* qkv_b = (const float*)d_in[6];
    const float* o_w   = (const float*)d_in[7];
    const float* ln2_g = (const float*)d_in[8];
    const float* ln2_b = (const float*)d_in[9];
    const float* p1_w  = (const float*)d_in[10];
    const float* p1_b  = (const float*)d_in[11];
    const float* p2_w  = (const float*)d_in[12];
    const float* p2_b  = (const float*)d_in[13];
    float* out = (float*)d_out;

    char* w = (char*)d_ws;
    auto take = [&](size_t bytes) -> char* {
        char* p = w;
        w += (bytes + 255) & ~(size_t)255;
        return p;
    };
    u16* qkvW   = (u16*)take((size_t)3072 * 1024 * 2);
    u16* oW     = (u16*)take((size_t)1024 * 1024 * 2);
    u16* p1W    = (u16*)take((size_t)4096 * 1024 * 2);
    u16* p2W    = (u16*)take((size_t)1024 * 4096 * 2);
    u16* Zn     = (u16*)take((size_t)4096 * 1024 * 2);   // reused for Zn2
    u16* Qb     = (u16*)take((size_t)32 * 2048 * 64 * 2);
    u16* Kb     = (u16*)take((size_t)32 * 2048 * 64 * 2);
    u16* Vt     = (u16*)take((size_t)32 * 64 * 2048 * 2);
    u16* attnL  = (u16*)take((size_t)4096 * 1024 * 2);
    float* Z1   = (float*)take((size_t)4096 * 1024 * 4);
    u16* hbuf   = (u16*)take((size_t)4096 * 4096 * 2);   // 33.55 MB
    unsigned* Mp = (unsigned*)take((size_t)2 * 2048 * 2048 * 4);  // 33.55 MB
    float* pbias = (float*)take((size_t)3072 * 4);
    float* Vsc    = (float*)hbuf;          // alias: dead before hbuf written
    float* part01 = (float*)Mp;            // alias: Mp dead after attention
    float* part23 = (float*)hbuf;          // alias: hbuf dead during o-proj

    // merged prep (casts + bias permute + mask pack)
    prep_all<<<dim3(20481), 256, 0, stream>>>(qkv_w, o_w, p1_w, p2_w, qkv_b, nmask, pmask,
                                              qkvW, oW, p1W, p2W, pbias, Mp);
    // LN1
    ln_bf16<<<dim3(4096), 256, 0, stream>>>(Z, ln1_g, ln1_b, Zn);
    // QKV projection: V -> f32 scratch, Q/K -> bf16 [BH][N][64]
    gemm_bt<0><<<dim3(24, 32), 256, 0, stream>>>(Zn, qkvW, pbias, Vsc, Qb, Kb, 4096, 3072, 1024, 1024);
    // V transpose -> Vt [BH][64][2048] (PV k-order columns)
    vtrans<<<dim3(32, 32), 256, 0, stream>>>(Vsc, Vt);
    // attention (4 blocks/CU, in-register softmax, no P exchange)
    attn_fused6<<<dim3(1024), 256, 0, stream>>>(Qb, Kb, Vt, Mp, attnL);
    // o-projection, split-K=4 -> f32 partials (p0,p1 in Mp; p2,p3 in hbuf)
    gemm_bt<4><<<dim3(8, 32, 4), 256, 0, stream>>>(attnL, oW, nullptr, part01, part23, nullptr,
                                                   4096, 1024, 256, 1024);
    // 4-way combine + residual + LN2 (writes Z1 and Zn)
    ln2_comb4<<<dim3(4096), 256, 0, stream>>>(part01, part01 + (size_t)4096 * 1024,
                                              part23, part23 + (size_t)4096 * 1024,
                                              Z, ln2_g, ln2_b, Z1, Zn);
    // MLP up + relu -> hbuf (bf16)
    gemm_bt<2><<<dim3(32, 32), 256, 0, stream>>>(Zn, p1W, p1_b, hbuf, nullptr, nullptr,
                                                 4096, 4096, 1024, 1024);
    // MLP down, split-K=2 -> f32 partials in Mp
    gemm_bt<4><<<dim3(8, 32, 2), 256, 0, stream>>>(hbuf, p2W, nullptr, part01, nullptr, nullptr,
                                                   4096, 1024, 2048, 4096);
    // final combine -> out
    out_comb<<<dim3(4096), 256, 0, stream>>>(part01, part01 + (size_t)4096 * 1024, p2_b, Z1, out);
}